// Round 11
// baseline (212.425 us; speedup 1.0000x reference)
//
#include <hip/hip_runtime.h>

// Shapes
#define NB   256      // batch
#define E0   300      // embedding
#define EP   304      // padded embedding
#define F_   512      // features
#define KP   1536     // padded K (5*304=1520 -> 24 supersteps of 64)
#define LQ_  64
#define LA_  256

typedef __attribute__((ext_vector_type(16))) float f32x16;
typedef __attribute__((ext_vector_type(8)))  short short8;

#define XQ_ELEMS (NB * (LQ_ + 4) * EP)   // 5,292,032
#define XA_ELEMS (NB * (LA_ + 4) * EP)   // 20,234,240
#define WF_ELEMS (F_ * KP)               // 786,432 (32x32-fragment-packed)
#define OUTQ_ELEMS ((size_t)NB * F_ * LQ_)
#define XROWS (NB * (LQ_ + 4) + NB * (LA_ + 4))   // 83,968

__device__ __forceinline__ unsigned short f2bf(float x) {
    unsigned int u = __float_as_uint(x);
    u = u + 0x7fffu + ((u >> 16) & 1u);   // RNE
    return (unsigned short)(u >> 16);
}

// Zero-padded bf16 x with halo, flat-indexed dense blocks. (Verified r6-r10.)
__global__ void prep_x(const float* __restrict__ q, const float* __restrict__ a,
                       unsigned short* __restrict__ xq, unsigned short* __restrict__ xa)
{
    int idx = blockIdx.x * 256 + threadIdx.x;
    if (idx >= XROWS * 76) return;
    int row = idx / 76;
    int col = idx - row * 76;

    const float* src;
    unsigned short* dst;
    bool valid;
    if (row < NB * (LQ_ + 4)) {
        int b = row / (LQ_ + 4), lp = row - b * (LQ_ + 4);
        dst = xq + (size_t)row * EP;
        valid = (lp >= 2 && lp < 2 + LQ_);
        src = q + ((size_t)b * LQ_ + (lp - 2)) * E0;
    } else {
        int r2 = row - NB * (LQ_ + 4);
        int b = r2 / (LA_ + 4), lp = r2 - b * (LA_ + 4);
        dst = xa + (size_t)r2 * EP;
        valid = (lp >= 2 && lp < 2 + LA_);
        src = a + ((size_t)b * LA_ + (lp - 2)) * E0;
    }
    unsigned long long pk = 0ull;
    if (valid && col < 75) {
        const float4 v = reinterpret_cast<const float4*>(src)[col];
        pk = (unsigned long long)f2bf(v.x)
           | ((unsigned long long)f2bf(v.y) << 16)
           | ((unsigned long long)f2bf(v.z) << 32)
           | ((unsigned long long)f2bf(v.w) << 48);
    }
    *reinterpret_cast<unsigned long long*>(dst + (size_t)col * 4) = pk;
}

// W packed as 32x32x16 A-fragments: layout [t32:16][kf:96][lane:64][8].
// Lane holds f = t32*32 + (lane&31), k' = kf*16 + (lane>>5)*8 + j.
// (Same lane-pattern family as the r1-verified 16x16x32 A-layout.)
__global__ void prep_w3(const float* __restrict__ W, unsigned short* __restrict__ wfr)
{
    int idx = blockIdx.x * 256 + threadIdx.x;     // grid = 786432/256
    int j    = idx & 7;
    int lane = (idx >> 3) & 63;
    int rem  = idx >> 9;          // global frag id 0..1535
    int kf   = rem % 96;
    int t32  = rem / 96;
    int f  = t32 * 32 + (lane & 31);
    int kp = kf * 16 + (lane >> 5) * 8 + j;
    int jj = kp / EP;
    int e  = kp - jj * EP;
    float v = (kp < 5 * EP && e < E0) ? W[(size_t)(jj * E0 + e) * F_ + f] : 0.f;
    wfr[idx] = f2bf(v);
}

// 128f x 128l block, 4 waves (wave = 32f x 128l via mfma_f32_32x32x16_bf16,
// acc = 4 x f32x16).  Superstep = 64 k (2 ksubs of 32).
// Z: ring-3 LDS (3 x 16 KB) via global_load_lds, staged 2 ss ahead.
// W: L2->reg (fragment-packed), set reloaded right after its last use ->
//    1-ss landing window, 2 sets ping-pong, no WAR.
// f-major grid (ftq = wg/640): co-resident blocks share ftq -> same W stream
// -> L1 serves most W traffic.
// Per-wave in-order VMEM ledger (ST4 = 4 GLLDS, W4 = 4 dwordx4):
//   prologue: [W4(0), ST4(0), ST4(1), W4(1)] -> vmcnt(8) retires W4(0)+ST4(0).
//   ss S: ST4(S+2)@start ... fence ... W4(S+2)@end.
//   Steady invariant entering S: [W4(S), ST4(S+1), W4(S+1)]; +ST4(S+2) = 16;
//   k0 fence vmcnt(8) retires W4(S) (used now) + ST4(S+1) (published by the
//   end-of-S barrier, read in S+1).  Ring-3 WAR: ST4(S+2) -> buf (S-1)%3,
//   whose reads drained at S-1's k1 lgkmcnt(0) before the end-of-(S-1)
//   barrier, after which the stage is issued.
//   Tail: S=22 fence vmcnt(4) (retires W4(22)+ST4(23)); S=23 vmcnt(0).
__global__ __launch_bounds__(256, 3) void qa_gemm(
    const unsigned short* __restrict__ xq,
    const unsigned short* __restrict__ xa,
    const unsigned short* __restrict__ wfr,
    const float* __restrict__ bias,
    float* __restrict__ out)
{
    __shared__ __align__(16) unsigned short lds[3 * 8192];   // 48 KB Z-ring

    const int bid = blockIdx.x;
    const int wg  = (bid & 7) * 320 + (bid >> 3);   // XCD swizzle, 2560 % 8 == 0

    const int ftq = wg / 640;        // f-quarter, SLOWEST -> co-resident share W
    const int lt  = wg - ftq * 640;  // l-tile of 128 rows

    const unsigned short* xp;
    float* ob;
    int Mbase, lsh, Lp;
    if (lt < 128) {                  // question region: 16384 rows
        Mbase = lt * 128;
        xp = xq; lsh = 6; Lp = LQ_ + 4;
        ob = out;
    } else {                         // answer region: 65536 rows
        Mbase = (lt - 128) * 128;
        xp = xa; lsh = 8; Lp = LA_ + 4;
        ob = out + OUTQ_ELEMS;
    }
    const int Lv = 1 << lsh;

    const int tid  = threadIdx.x;
    const int lane = tid & 63;
    const int wid  = tid >> 6;       // wave = 32f slice
    const int l31  = lane & 31;
    const int lhi  = lane >> 5;

    // ---- Z staging geometry (swizzle verified r1-r10): wave stages rows
    //      wid*32 .. +31 per ksub as 2 GLLDS of 16 rows.
    const int s_c  = (lane & 3) ^ ((lane >> 3) & 3);
    const int sub  = lane >> 2;
    const int mrA = Mbase + wid * 32 + sub;
    const int mrB = mrA + 16;
    const unsigned short* gZ0 = xp + (size_t)((mrA >> lsh) * Lp + (mrA & (Lv - 1))) * EP + s_c * 8;
    const unsigned short* gZ1 = xp + (size_t)((mrB >> lsh) * Lp + (mrB & (Lv - 1))) * EP + s_c * 8;
    const int dzA = wid * 1024;      // shorts within a 4096-short ksub block
    const int dzB = dzA + 512;

#define GLLDS(p, d) __builtin_amdgcn_global_load_lds(                               \
        (const __attribute__((address_space(1))) void*)(p),                         \
        (__attribute__((address_space(3))) void*)(d), 16, 0, 0)
// Stage tile T (k' = T*64..+63) into ring buf at short-offset RB.
#define ST4(RB, T) do { const size_t ko = (size_t)(T) * 64;                         \
    GLLDS(gZ0 + ko,      lds + (RB) + dzA);                                         \
    GLLDS(gZ1 + ko,      lds + (RB) + dzB);                                         \
    GLLDS(gZ0 + ko + 32, lds + (RB) + 4096 + dzA);                                  \
    GLLDS(gZ1 + ko + 32, lds + (RB) + 4096 + dzB); } while (0)

    // ---- W fragment stream (frag = 512 shorts; ss consumes 4 frags)
    const unsigned short* wp = wfr + (size_t)(ftq * 4 + wid) * (96 * 512) + lane * 8;

#define WLOAD(dst, p) do {                                                           \
    asm volatile("global_load_dwordx4 %0, %1, off" : "=v"(dst) : "v"(p) : "memory"); \
    (p) += 512; } while (0)
#define W4(SET) do { WLOAD(SET[0], wp); WLOAD(SET[1], wp);                           \
                     WLOAD(SET[2], wp); WLOAD(SET[3], wp); } while (0)

    // ---- Z B-frag offsets (bytes within a ksub block), chunk-swizzled:
    // src chunk cS = ks*2 + lhi of row nt*32+l31 is stored at cS ^ ((row>>1)&3).
    const int swr = (l31 >> 1) & 3;
    int boff[4][2];
#pragma unroll
    for (int nt = 0; nt < 4; ++nt)
#pragma unroll
        for (int ks = 0; ks < 2; ++ks)
            boff[nt][ks] = (nt * 32 + l31) * 64 + ((ks * 2 + lhi) ^ swr) * 16;

    f32x16 acc[4] = {};
    short8 wA[4], wB[4], bfr[4][2];

#define MFMA32(a, b, c) __builtin_amdgcn_mfma_f32_32x32x16_bf16((a), (b), (c), 0, 0, 0)
#define RDB(BB) do { _Pragma("unroll") for (int nt = 0; nt < 4; ++nt)               \
    _Pragma("unroll") for (int ks = 0; ks < 2; ++ks)                                \
        bfr[nt][ks] = *(const short8*)((BB) + boff[nt][ks]); } while (0)
#define MFMA8(C, SET) do { _Pragma("unroll") for (int nt = 0; nt < 4; ++nt) {       \
        acc[nt] = MFMA32(SET[2 * (C) + 0], bfr[nt][0], acc[nt]);                    \
        acc[nt] = MFMA32(SET[2 * (C) + 1], bfr[nt][1], acc[nt]);                    \
    } } while (0)
#define SB __builtin_amdgcn_sched_barrier(0)
#define SP1 __builtin_amdgcn_s_setprio(1)
#define SP0 __builtin_amdgcn_s_setprio(0)

    int rbPrev = 16384, rbCur = 0, rbNext = 8192;   // short offsets of ring bufs

    // One superstep.  VM = k0-fence vmcnt literal.
#define SS(SET, DO_ST, DO_W, TT, VM)                                                \
{   if (DO_ST) ST4(rbPrev, TT);                                                     \
    const char* bb = (const char*)(lds + rbCur);                                    \
    RDB(bb);                                                                        \
    asm volatile("s_waitcnt vmcnt(" #VM ") lgkmcnt(0)" ::: "memory"); SB;           \
    SP1; MFMA8(0, SET); SP0; SB;                                                    \
    RDB(bb + 8192);                                                                 \
    asm volatile("s_waitcnt lgkmcnt(0)" ::: "memory"); SB;                          \
    SP1; MFMA8(1, SET); SP0; SB;                                                    \
    if (DO_W) W4(SET);                                                              \
    asm volatile("s_barrier" ::: "memory");                                         \
    { int _t = rbPrev; rbPrev = rbCur; rbCur = rbNext; rbNext = _t; }               \
}

    // Prologue
    W4(wA); ST4(0, 0); ST4(8192, 1); W4(wB);
    asm volatile("s_waitcnt vmcnt(8)\n\ts_barrier" ::: "memory");

    for (int S = 0; S < 22; S += 2) {
        SS(wA, 1, 1, S + 2, 8);
        SS(wB, 1, 1, S + 3, 8);
    }
    SS(wA, 0, 0, 0, 4);    // S = 22
    SS(wB, 0, 0, 0, 0);    // S = 23

#undef SS
#undef MFMA8
#undef RDB
#undef MFMA32
#undef W4
#undef WLOAD
#undef ST4
#undef GLLDS

    // ---- epilogue: 32x32 C/D layout (m74/m101-verified):
    //      col(l) = lane&31, row(f) = (reg&3) + 8*(reg>>2) + 4*(lane>>5)
    const int fwbase = ftq * 128 + wid * 32;
#pragma unroll
    for (int nt = 0; nt < 4; ++nt) {
        const int m = Mbase + nt * 32 + l31;
        const int b = m >> lsh;
        const int lcol = m & (Lv - 1);
        float* orow = ob + ((size_t)b * F_ << lsh) + lcol;
        const f32x16 v = acc[nt];
#pragma unroll
        for (int reg = 0; reg < 16; ++reg) {
            const int f = fwbase + (reg & 3) + 8 * (reg >> 2) + 4 * lhi;
            orow[(size_t)f << lsh] = v[reg] + __ldg(&bias[f]);
        }
    }
}

extern "C" void kernel_launch(void* const* d_in, const int* in_sizes, int n_in,
                              void* d_out, int out_size, void* d_ws, size_t ws_size,
                              hipStream_t stream)
{
    const float* q    = (const float*)d_in[0];
    const float* a    = (const float*)d_in[1];
    const float* W    = (const float*)d_in[2];
    const float* bias = (const float*)d_in[3];
    float* out = (float*)d_out;

    unsigned short* xq  = (unsigned short*)d_ws;
    unsigned short* xa  = xq + XQ_ELEMS;
    unsigned short* wfr = xa + XA_ELEMS;
    // ws needed: (XQ+XA+WF)*2 = 52.6 MB.  xa K-pad tail reads overrun <=32 B
    // into wfr: in-bounds; the matching W fragments are zero -> don't-care.

    prep_x<<<(XROWS * 76 + 255) / 256, 256, 0, stream>>>(q, a, xq, xa);
    prep_w3<<<WF_ELEMS / 256, 256, 0, stream>>>(W, wfr);
    qa_gemm<<<2560, 256, 0, stream>>>(xq, xa, wfr, bias, out);
}

// Round 12
// 181.004 us; speedup vs baseline: 1.1736x; 1.1736x over previous
//
#include <hip/hip_runtime.h>

// Shapes
#define NB   256      // batch
#define E0   300      // embedding
#define EP   304      // padded embedding
#define F_   512      // features
#define KP   1536     // padded K (5*304=1520 -> 48 ksubs of 32 / 12 ss of 128)
#define LQ_  64
#define LA_  256

typedef __attribute__((ext_vector_type(16))) float f32x16;
typedef __attribute__((ext_vector_type(8)))  short short8;

#define XQ_ELEMS (NB * (LQ_ + 4) * EP)   // 5,292,032
#define XA_ELEMS (NB * (LA_ + 4) * EP)   // 20,234,240
#define WF_ELEMS (F_ * KP)               // 786,432 (32x32-fragment-packed)
#define OUTQ_ELEMS ((size_t)NB * F_ * LQ_)
#define XROWS (NB * (LQ_ + 4) + NB * (LA_ + 4))   // 83,968

__device__ __forceinline__ unsigned short f2bf(float x) {
    unsigned int u = __float_as_uint(x);
    u = u + 0x7fffu + ((u >> 16) & 1u);   // RNE
    return (unsigned short)(u >> 16);
}

// Zero-padded bf16 x with halo, flat-indexed dense blocks. (Verified r6-r11.)
__global__ void prep_x(const float* __restrict__ q, const float* __restrict__ a,
                       unsigned short* __restrict__ xq, unsigned short* __restrict__ xa)
{
    int idx = blockIdx.x * 256 + threadIdx.x;
    if (idx >= XROWS * 76) return;
    int row = idx / 76;
    int col = idx - row * 76;

    const float* src;
    unsigned short* dst;
    bool valid;
    if (row < NB * (LQ_ + 4)) {
        int b = row / (LQ_ + 4), lp = row - b * (LQ_ + 4);
        dst = xq + (size_t)row * EP;
        valid = (lp >= 2 && lp < 2 + LQ_);
        src = q + ((size_t)b * LQ_ + (lp - 2)) * E0;
    } else {
        int r2 = row - NB * (LQ_ + 4);
        int b = r2 / (LA_ + 4), lp = r2 - b * (LA_ + 4);
        dst = xa + (size_t)r2 * EP;
        valid = (lp >= 2 && lp < 2 + LA_);
        src = a + ((size_t)b * LA_ + (lp - 2)) * E0;
    }
    unsigned long long pk = 0ull;
    if (valid && col < 75) {
        const float4 v = reinterpret_cast<const float4*>(src)[col];
        pk = (unsigned long long)f2bf(v.x)
           | ((unsigned long long)f2bf(v.y) << 16)
           | ((unsigned long long)f2bf(v.z) << 32)
           | ((unsigned long long)f2bf(v.w) << 48);
    }
    *reinterpret_cast<unsigned long long*>(dst + (size_t)col * 4) = pk;
}

// W packed as 32x32x16 A-fragments: layout [t32:16][kf:96][lane:64][8].
// Lane holds f = t32*32 + (lane&31), k' = kf*16 + (lane>>5)*8 + j.
// (Hardware-verified in r11: kernel passed with this layout.)
__global__ void prep_w3(const float* __restrict__ W, unsigned short* __restrict__ wfr)
{
    int idx = blockIdx.x * 256 + threadIdx.x;     // grid = 786432/256
    int j    = idx & 7;
    int lane = (idx >> 3) & 63;
    int rem  = idx >> 9;          // global frag id 0..1535
    int kf   = rem % 96;
    int t32  = rem / 96;
    int f  = t32 * 32 + (lane & 31);
    int kp = kf * 16 + (lane >> 5) * 8 + j;
    int jj = kp / EP;
    int e  = kp - jj * EP;
    float v = (kp < 5 * EP && e < E0) ? W[(size_t)(jj * E0 + e) * F_ + f] : 0.f;
    wfr[idx] = f2bf(v);
}

// r8 skeleton + 32x32 datapath.
// 256f x 64l block, 4 waves (wave = 64f x 64l via mfma_f32_32x32x16_bf16,
// acc[2][2] f32x16).  BK=128 supersteps (4 ksubs of 32), ring-2 LDS (32 KB).
// Z: staged via global_load_lds exactly as r8 (same geometry, same swizzle).
// W: L2->reg ping-pong at ksub granularity (4 frags = 4 KB per wave-ksub,
//    same VMEM unit count as r8 -> the r8 fence ledger carries over verbatim):
//   prologue: [W4(k0), stage(ss0)x4] -> vmcnt(0), barrier.
//   ss S: ZRD(blk0); stage(S+1)x4; ks0: ZRD(blk1)+W4 -> vmcnt(8) lgkm(4);
//   ks1: ZRD(blk2)+W4 -> vmcnt(4) lgkm(4); ks2: ZRD(blk3)+W4 -> vmcnt(4)
//   lgkm(4); ks3: W4 -> vmcnt(4) lgkm(0); s_barrier.
//   S=11: no stage; (4,4),(4,4),(4,4),(0,0).
// Ring-2 WAR/publication arguments identical to r8 (passed r8/r9 harness).
__global__ __launch_bounds__(256, 3) void qa_gemm(
    const unsigned short* __restrict__ xq,
    const unsigned short* __restrict__ xa,
    const unsigned short* __restrict__ wfr,
    const float* __restrict__ bias,
    float* __restrict__ out)
{
    __shared__ __align__(16) unsigned short lds[2 * 8192];   // 32 KB Z-ring

    const int bid = blockIdx.x;
    const int wg  = (bid & 7) * 320 + (bid >> 3);   // XCD swizzle, 2560 % 8 == 0

    const unsigned short* xp;
    float* ob;
    int Mbase, lsh, Lp, ftBase;
    if (wg < 512) {                 // question: 256 l-tiles x 2 f-halves
        Mbase  = (wg >> 1) * 64;
        ftBase = (wg & 1) * 256;
        xp = xq; lsh = 6; Lp = LQ_ + 4;
        ob = out;
    } else {                        // answer: 1024 l-tiles x 2 f-halves
        const int id = wg - 512;
        Mbase  = (id >> 1) * 64;
        ftBase = (id & 1) * 256;
        xp = xa; lsh = 8; Lp = LA_ + 4;
        ob = out + OUTQ_ELEMS;
    }
    const int Lv = 1 << lsh;

    const int tid  = threadIdx.x;
    const int lane = tid & 63;
    const int wid  = tid >> 6;      // wave = 64f slice; all share the 64l tile
    const int l31  = lane & 31;
    const int lhi  = lane >> 5;

    // ---- Z staging geometry (byte-identical to r8): wave stages 16 rows/ksub
    const int s_c  = (lane & 3) ^ ((lane >> 3) & 3);
    const int sub  = lane >> 2;
    const int mr0 = Mbase + wid * 16 + sub;
    const unsigned short* gZ0 = xp + (size_t)((mr0 >> lsh) * Lp + (mr0 & (Lv - 1))) * EP + s_c * 8;
    const int dz0 = wid * 512;      // shorts, within each 2048-short ksub block

#define GLLDS(p, d) __builtin_amdgcn_global_load_lds(                               \
        (const __attribute__((address_space(1))) void*)(p),                         \
        (__attribute__((address_space(3))) void*)(d), 16, 0, 0)
// Stage super-tile T (k' = T*128..+127) into buf T&1 as 4 ksub blocks of [64][32]
#define STAGE_SS(T) do { const int rb = ((T) & 1) * 8192; const size_t ko = (size_t)(T) * 128; \
    GLLDS(gZ0 + ko +  0, lds + rb + 0 * 2048 + dz0);                                \
    GLLDS(gZ0 + ko + 32, lds + rb + 1 * 2048 + dz0);                                \
    GLLDS(gZ0 + ko + 64, lds + rb + 2 * 2048 + dz0);                                \
    GLLDS(gZ0 + ko + 96, lds + rb + 3 * 2048 + dz0); } while (0)

    // ---- W fragment pointers: wave covers t32a = f rows +0..31, t32b = +32..63
    const int t32a = (ftBase >> 5) + wid * 2;
    const unsigned short* wpA0 = wfr + ((size_t)t32a * 96 + 0) * 512 + lane * 8;
    const unsigned short* wpA1 = wpA0 + 512;
    const unsigned short* wpB0 = wfr + ((size_t)(t32a + 1) * 96 + 0) * 512 + lane * 8;
    const unsigned short* wpB1 = wpB0 + 512;

#define WLOAD(dst, p) do {                                                           \
    asm volatile("global_load_dwordx4 %0, %1, off" : "=v"(dst) : "v"(p) : "memory"); \
    (p) += 1024; } while (0)
// One ksub's W group: (t32a,ks0),(t32a,ks1),(t32b,ks0),(t32b,ks1)
#define W4(SET) do { WLOAD(SET[0], wpA0); WLOAD(SET[1], wpA1);                       \
                     WLOAD(SET[2], wpB0); WLOAD(SET[3], wpB1); } while (0)

    // ---- Z B-frag offsets within a ksub block (bytes): frag (nt, ks16):
    // row = nt*32 + l31, chunk c = ks16*2 + lhi stored at c ^ ((row>>1)&3).
    const int swr = (l31 >> 1) & 3;
    int boff[4];                    // index nt*2 + ks16
#pragma unroll
    for (int nt = 0; nt < 2; ++nt)
#pragma unroll
        for (int ks = 0; ks < 2; ++ks)
            boff[nt * 2 + ks] = (nt * 32 + l31) * 64 + ((ks * 2 + lhi) ^ swr) * 16;

    f32x16 acc[2][2] = {};          // [mf][nt]
    short8 zA[4], zB[4], wA[4], wB[4];

#define MFMA32(a, b, c) __builtin_amdgcn_mfma_f32_32x32x16_bf16((a), (b), (c), 0, 0, 0)
#define ZRD(DST, BLK) do { _Pragma("unroll") for (int i = 0; i < 4; ++i)             \
    DST[i] = *(const short8*)(bb + (BLK) * 4096 + boff[i]); } while (0)

    // One ksub: read next-ksub Z frags, load next W group, counted fence, 8 MFMA.
#define KSUB(NXT, ZU, ZL, WU, WL, DO_ZRD, DO_W, VMCV, LGKV) do {                    \
    if (DO_ZRD) { ZRD(ZL, NXT); }                                                   \
    if (DO_W) { W4(WL); }                                                           \
    asm volatile("s_waitcnt vmcnt(" #VMCV ") lgkmcnt(" #LGKV ")" ::: "memory");     \
    __builtin_amdgcn_sched_barrier(0);                                              \
    __builtin_amdgcn_s_setprio(1);                                                  \
    acc[0][0] = MFMA32(WU[0], ZU[0], acc[0][0]);                                    \
    acc[0][0] = MFMA32(WU[1], ZU[1], acc[0][0]);                                    \
    acc[0][1] = MFMA32(WU[0], ZU[2], acc[0][1]);                                    \
    acc[0][1] = MFMA32(WU[1], ZU[3], acc[0][1]);                                    \
    acc[1][0] = MFMA32(WU[2], ZU[0], acc[1][0]);                                    \
    acc[1][0] = MFMA32(WU[3], ZU[1], acc[1][0]);                                    \
    acc[1][1] = MFMA32(WU[2], ZU[2], acc[1][1]);                                    \
    acc[1][1] = MFMA32(WU[3], ZU[3], acc[1][1]);                                    \
    __builtin_amdgcn_s_setprio(0);                                                  \
    __builtin_amdgcn_sched_barrier(0);                                              \
} while (0)

    // Prologue: W(k0) -> wA, stage(ss0); drain; publish.
    W4(wA);
    STAGE_SS(0);
    asm volatile("s_waitcnt vmcnt(0)\n\ts_barrier" ::: "memory");

    for (int S = 0; S < 11; ++S) {
        const char* bb = (const char*)lds + (S & 1) * 16384;
        ZRD(zA, 0);
        STAGE_SS(S + 1);
        KSUB(1, zA, zB, wA, wB, 1, 1, 8, 4);   // ks0
        KSUB(2, zB, zA, wB, wA, 1, 1, 4, 4);   // ks1 (forces stage(S+1))
        KSUB(3, zA, zB, wA, wB, 1, 1, 4, 4);   // ks2
        KSUB(0, zB, zA, wB, wA, 0, 1, 4, 0);   // ks3 (loads next-ss k0)
        asm volatile("s_barrier" ::: "memory");
    }
    {   // S = 11: no stage, W chain ends at k47
        const char* bb = (const char*)lds + 16384;
        ZRD(zA, 0);
        KSUB(1, zA, zB, wA, wB, 1, 1, 4, 4);   // ks0 (loads k45)
        KSUB(2, zB, zA, wB, wA, 1, 1, 4, 4);   // ks1 (loads k46)
        KSUB(3, zA, zB, wA, wB, 1, 1, 4, 4);   // ks2 (loads k47)
        KSUB(0, zB, zA, wB, wA, 0, 0, 0, 0);   // ks3
    }

#undef KSUB
#undef ZRD
#undef MFMA32
#undef W4
#undef WLOAD
#undef STAGE_SS
#undef GLLDS

    // ---- epilogue: 32x32 C/D layout (m74/m101 + r11 hardware-verified):
    //      col(l) = lane&31, row(f) = (reg&3) + 8*(reg>>2) + 4*(lane>>5)
#pragma unroll
    for (int nt = 0; nt < 2; ++nt) {
        const int m = Mbase + nt * 32 + l31;
        const int b = m >> lsh;
        const int lcol = m & (Lv - 1);
        float* orow = ob + ((size_t)b * F_ << lsh) + lcol;
#pragma unroll
        for (int mf = 0; mf < 2; ++mf) {
            const int fbase = ftBase + wid * 64 + mf * 32 + 4 * lhi;
            const f32x16 v = acc[mf][nt];
#pragma unroll
            for (int reg = 0; reg < 16; ++reg) {
                const int f = fbase + (reg & 3) + 8 * (reg >> 2);
                orow[(size_t)f << lsh] = v[reg] + __ldg(&bias[f]);
            }
        }
    }
}

extern "C" void kernel_launch(void* const* d_in, const int* in_sizes, int n_in,
                              void* d_out, int out_size, void* d_ws, size_t ws_size,
                              hipStream_t stream)
{
    const float* q    = (const float*)d_in[0];
    const float* a    = (const float*)d_in[1];
    const float* W    = (const float*)d_in[2];
    const float* bias = (const float*)d_in[3];
    float* out = (float*)d_out;

    unsigned short* xq  = (unsigned short*)d_ws;
    unsigned short* xa  = xq + XQ_ELEMS;
    unsigned short* wfr = xa + XA_ELEMS;
    // ws needed: (XQ+XA+WF)*2 = 52.6 MB.  xa K-pad tail reads overrun <=32 B
    // into wfr: in-bounds; the matching W fragments are zero -> don't-care.

    prep_x<<<(XROWS * 76 + 255) / 256, 256, 0, stream>>>(q, a, xq, xa);
    prep_w3<<<WF_ELEMS / 256, 256, 0, stream>>>(W, wfr);
    qa_gemm<<<2560, 256, 0, stream>>>(xq, xa, wfr, bias, out);
}